// Round 2
// baseline (1443.258 us; speedup 1.0000x reference)
//
#include <hip/hip_runtime.h>

// All float tensors f32 (established rounds 0-4). H=1024,E=512,A=512,L=512.
// enc_seq_len==1 -> reference row-mask is a no-op.
#define V 50257
#define NBLK 1024

// ---------------- workspace layout (f32 words) ----------------
#define WS_PRE    0      // attn_pre (512)
#define WS_ATTNW  512    // softmax weights (512)
#define WS_APPL   1024   // attn_applied (1024)
#define WS_X      2048   // combine+relu output (1024)
#define WS_GHH    3072   // W_hh·h0 + b_hh (4096)
#define WS_BAR    8192   // grid-barrier state (2 ints), init_k zeroes it

// output layout (f32): logits[50257], h_new[1024], c_new[1024], attn_w[512]
#define OUT_H     50257
#define OUT_C     51281
#define OUT_AW    52305

__device__ __forceinline__ float4 ld4(const float* p) {
  return *reinterpret_cast<const float4*>(p);
}
__device__ __forceinline__ float dot4(float4 a, float4 b) {
  return a.x * b.x + a.y * b.y + a.z * b.z + a.w * b.w;
}
__device__ __forceinline__ float wave_reduce(float a) {
#pragma unroll
  for (int off = 32; off > 0; off >>= 1) a += __shfl_xor(a, off, 64);
  return a;
}
__device__ __forceinline__ float sigf(float v) {
  return 1.f / (1.f + expf(-v));
}

// Software grid barrier (sense-reversing, device scope). All NBLK blocks are
// co-resident (exact-fit grid at 4 blocks/CU), so the spin always terminates;
// a generous iteration cap turns any residency surprise into a fast wrong-
// answer fail instead of a hang.
__device__ __forceinline__ void grid_bar(int* bar) {
  __syncthreads();
  if (threadIdx.x == 0) {
    __threadfence();  // agent-scope release: write back this XCD's L2
    int g = __hip_atomic_load(bar + 1, __ATOMIC_RELAXED, __HIP_MEMORY_SCOPE_AGENT);
    int a = __hip_atomic_fetch_add(bar, 1, __ATOMIC_ACQ_REL, __HIP_MEMORY_SCOPE_AGENT);
    if (a == NBLK - 1) {
      __hip_atomic_store(bar, 0, __ATOMIC_RELAXED, __HIP_MEMORY_SCOPE_AGENT);
      __hip_atomic_store(bar + 1, g + 1, __ATOMIC_RELEASE, __HIP_MEMORY_SCOPE_AGENT);
    } else {
      long spin = 0;
      while (__hip_atomic_load(bar + 1, __ATOMIC_ACQUIRE, __HIP_MEMORY_SCOPE_AGENT) == g) {
        __builtin_amdgcn_s_sleep(2);
        if (++spin > 4000000L) break;  // ~0.2 s: fail fast, never hang
      }
    }
    __threadfence();
  }
  __syncthreads();
}

// Stream rows [row0, row0+nrows) of a [*,1024]-f32 matrix through the caches.
// Loads kept live via empty asm so the compiler can't DCE them (rule #17).
__device__ __forceinline__ void prefetch_rows(const float* __restrict__ W,
                                              int row0, int nrows,
                                              int bid, int nb, int t) {
  const float4* p = reinterpret_cast<const float4*>(W) + (size_t)row0 * 256;
  size_t n4 = (size_t)nrows * 256;
  float sx = 0.f, sy = 0.f, sz = 0.f, sw = 0.f;
  for (size_t i = (size_t)bid * 256 + t; i < n4; i += (size_t)nb * 256) {
    float4 v = p[i];
    sx += v.x; sy += v.y; sz += v.z; sw += v.w;
  }
  asm volatile("" :: "v"(sx), "v"(sy), "v"(sz), "v"(sw));
}

// Zero barrier state + applied accumulator (ws is re-poisoned every iteration).
__global__ __launch_bounds__(256) void init_k(float* __restrict__ ws) {
  int t = threadIdx.x;
  if (t < 2) reinterpret_cast<int*>(ws + WS_BAR)[t] = 0;
  for (int i = t; i < 1024; i += 256) ws[WS_APPL + i] = 0.f;
}

// One fused kernel, 1024 blocks x 256 threads, exact-fit 4 blocks/CU.
__global__ __launch_bounds__(256, 4) void fused_k(
    const int* __restrict__ word, const float* __restrict__ av,
    const float* __restrict__ h0, const float* __restrict__ c0,
    const float* __restrict__ enc, const float* __restrict__ emb,
    const float* __restrict__ attn_W, const float* __restrict__ attn_b,
    const float* __restrict__ comb_W, const float* __restrict__ comb_b,
    const float* __restrict__ W_ih, const float* __restrict__ W_hh,
    const float* __restrict__ b_ih, const float* __restrict__ b_hh,
    const float* __restrict__ out_W, const float* __restrict__ out_b,
    float* __restrict__ ws, float* __restrict__ out) {
  int* bar = reinterpret_cast<int*>(ws + WS_BAR);
  const int b = blockIdx.x;        // 0..1023
  const int t = threadIdx.x;       // 0..255
  const int wv = t >> 6, lane = t & 63;
  const float* er = emb + (size_t)word[0] * 512;

  // ---- Phase A: attn_pre ∥ ghh=W_hh·h0+b_hh ∥ prefetch out_W[0:6144) ----
  if (b < 128) {
    int row = b * 4 + wv;                       // 512 rows
    const float* Wr = attn_W + (size_t)row * 1536;
    float acc = 0.f;
#pragma unroll
    for (int k = 0; k < 2; k++) {               // cols 0..511: embedded
      int c = lane * 4 + k * 256;
      acc += dot4(ld4(Wr + c), ld4(er + c));
    }
#pragma unroll
    for (int k = 2; k < 6; k++) {               // cols 512..1535: h0
      int c = lane * 4 + k * 256;
      acc += dot4(ld4(Wr + c), ld4(h0 + c - 512));
    }
    acc = wave_reduce(acc);
    if (lane == 0) ws[WS_PRE + row] = acc + attn_b[row];
  } else if (b < 256) {
    // ghh: 512 waves x 8 rows = 4096 gate rows (h0 is an input, no dep on x)
    int gid = (b - 128) * 4 + wv;
#pragma unroll
    for (int rr = 0; rr < 8; rr++) {
      int r = gid * 8 + rr;
      const float* Wh = W_hh + (size_t)r * 1024;
      float acc = 0.f;
#pragma unroll
      for (int k = 0; k < 4; k++) {
        int c = lane * 4 + k * 256;
        acc += dot4(ld4(Wh + c), ld4(h0 + c));
      }
      acc = wave_reduce(acc);
      if (lane == 0) ws[WS_GHH + r] = acc + b_hh[r];
    }
  } else {
    prefetch_rows(out_W, 0, 6144, b - 256, 768, t);      // 25 MB
  }
  grid_bar(bar);

  // ---- Phase B: softmax (block 0) ∥ prefetch out_W[6144:10240) ----
  if (b == 0) {
    __shared__ float red[4];
    __shared__ float stat[2];
    float v0 = ws[WS_PRE + t], v1 = ws[WS_PRE + 256 + t];
    float m = fmaxf(v0, v1);
#pragma unroll
    for (int off = 32; off > 0; off >>= 1) m = fmaxf(m, __shfl_xor(m, off, 64));
    if (lane == 0) red[wv] = m;
    __syncthreads();
    if (t == 0) stat[0] = fmaxf(fmaxf(red[0], red[1]), fmaxf(red[2], red[3]));
    __syncthreads();
    float e0 = expf(v0 - stat[0]), e1 = expf(v1 - stat[0]);
    float s = e0 + e1;
#pragma unroll
    for (int off = 32; off > 0; off >>= 1) s += __shfl_xor(s, off, 64);
    if (lane == 0) red[wv] = s;
    __syncthreads();
    if (t == 0) stat[1] = red[0] + red[1] + red[2] + red[3];
    __syncthreads();
    float w0 = e0 / stat[1], w1 = e1 / stat[1];
    ws[WS_ATTNW + t] = w0;
    ws[WS_ATTNW + 256 + t] = w1;
    out[OUT_AW + t] = w0;
    out[OUT_AW + 256 + t] = w1;
  } else {
    prefetch_rows(out_W, 6144, 4096, b - 1, 1023, t);    // 16.8 MB
  }
  grid_bar(bar);

  // ---- Phase C: attn_apply (32 blocks) ∥ prefetch out_W[10240:14336) ----
  if (b < 32) {
    int jb = b & 3, lb = b >> 2;
    int j = jb * 256 + t, l0 = lb * 64;
    float acc = 0.f;
#pragma unroll 4
    for (int l = l0; l < l0 + 64; l++)
      acc += ws[WS_ATTNW + l] * enc[(size_t)l * 1024 + j];
    atomicAdd(ws + WS_APPL + j, acc);
  } else {
    prefetch_rows(out_W, 10240, 4096, b - 32, 992, t);   // 16.8 MB
  }
  grid_bar(bar);

  // ---- Phase D: combine+relu (256 blocks) ∥ prefetch out_W[14336:18432) ----
  if (b < 256) {
    int row = b * 4 + wv;                       // 1024 rows
    const float* Wr = comb_W + (size_t)row * 2048;
    float acc = 0.f;
#pragma unroll
    for (int k = 0; k < 2; k++) {               // embedded
      int c = lane * 4 + k * 256;
      acc += dot4(ld4(Wr + c), ld4(er + c));
    }
#pragma unroll
    for (int k = 2; k < 6; k++) {               // applied
      int c = lane * 4 + k * 256;
      acc += dot4(ld4(Wr + c), ld4(ws + WS_APPL + c - 512));
    }
#pragma unroll
    for (int k = 6; k < 8; k++) {               // av_emb
      int c = lane * 4 + k * 256;
      acc += dot4(ld4(Wr + c), ld4(av + c - 1536));
    }
    acc = wave_reduce(acc);
    if (lane == 0) ws[WS_X + row] = fmaxf(acc + comb_b[row], 0.f);
  } else {
    prefetch_rows(out_W, 14336, 4096, b - 256, 768, t);  // 16.8 MB
  }
  grid_bar(bar);

  // ---- Phase E: gates = W_ih·x + b_ih + ghh; LSTM pointwise (block = t idx) --
  {
    __shared__ float gsh[4];
    size_t r = (size_t)wv * 1024 + b;           // wv: 0=i 1=f 2=g 3=o
    const float* Wi = W_ih + r * 1024;
    float acc = 0.f;
#pragma unroll
    for (int k = 0; k < 4; k++) {
      int c = lane * 4 + k * 256;
      acc += dot4(ld4(Wi + c), ld4(ws + WS_X + c));
    }
    acc = wave_reduce(acc);
    if (lane == 0) gsh[wv] = acc + b_ih[r] + ws[WS_GHH + r];
    __syncthreads();
    if (t == 0) {
      float gi = sigf(gsh[0]);
      float gf = sigf(gsh[1]);
      float gg = tanhf(gsh[2]);
      float go = sigf(gsh[3]);
      float cn = gf * c0[b] + gi * gg;
      float hn = go * tanhf(cn);
      out[OUT_H + b] = hn;
      out[OUT_C + b] = cn;
    }
  }
  grid_bar(bar);

  // ---- Phase F: logits, grid-stride, 8 rows/block-iter (2/wave) ----
  const float* hx = out + OUT_H;
  for (int g = b; g < 6283; g += NBLK) {
    int r0 = g * 8 + wv * 2;
    if (r0 >= V) continue;
    bool has1 = (r0 + 1) < V;
    const float* W0 = out_W + (size_t)r0 * 1024;
    float a0 = 0.f, a1 = 0.f;
#pragma unroll
    for (int k = 0; k < 4; k++) {
      int c = lane * 4 + k * 256;
      float4 xv = ld4(hx + c);
      a0 += dot4(ld4(W0 + c), xv);
      if (has1) a1 += dot4(ld4(W0 + 1024 + c), xv);
    }
    a0 = wave_reduce(a0);
    a1 = wave_reduce(a1);
    if (lane == 0) {
      out[r0] = a0 + out_b[r0];
      if (has1) out[r0 + 1] = a1 + out_b[r0 + 1];
    }
  }
}

extern "C" void kernel_launch(void* const* d_in, const int* in_sizes, int n_in,
                              void* d_out, int out_size, void* d_ws, size_t ws_size,
                              hipStream_t stream) {
  const int*   word   = (const int*)  d_in[0];
  // d_in[1] = enc_seq_len (==1 -> reference row-mask is a no-op)
  const float* av     = (const float*)d_in[2];
  const float* h0     = (const float*)d_in[3];
  const float* c0     = (const float*)d_in[4];
  const float* enc    = (const float*)d_in[5];
  const float* emb    = (const float*)d_in[6];
  const float* attn_W = (const float*)d_in[7];
  const float* attn_b = (const float*)d_in[8];
  const float* comb_W = (const float*)d_in[9];
  const float* comb_b = (const float*)d_in[10];
  const float* W_ih   = (const float*)d_in[11];
  const float* W_hh   = (const float*)d_in[12];
  const float* b_ih   = (const float*)d_in[13];
  const float* b_hh   = (const float*)d_in[14];
  const float* out_W  = (const float*)d_in[15];
  const float* out_b  = (const float*)d_in[16];

  float* ws  = (float*)d_ws;
  float* out = (float*)d_out;

  init_k<<<1, 256, 0, stream>>>(ws);
  fused_k<<<NBLK, 256, 0, stream>>>(word, av, h0, c0, enc, emb, attn_W, attn_b,
                                    comb_W, comb_b, W_ih, W_hh, b_ih, b_hh,
                                    out_W, out_b, ws, out);
}

// Round 3
// 394.944 us; speedup vs baseline: 3.6543x; 3.6543x over previous
//
#include <hip/hip_runtime.h>

// All float tensors f32 (established rounds 0-4). H=1024,E=512,A=512,L=512.
// enc_seq_len==1 -> reference row-mask is a no-op.
// R2 lesson: software grid barriers cost ~200us each on MI355X (1024 atomics
// serializing cross-XCD). Stay multi-kernel; sync at dispatch boundaries.
#define V 50257

// ---------------- workspace layout (f32 words) ----------------
#define WS_PRE    0      // attn_pre (512)
#define WS_APPL   1024   // attn_applied (1024)
#define WS_X      2048   // combine+relu output (1024)
#define WS_GHH    3072   // W_hh·h0 + b_hh (4096)

// output layout (f32): logits[50257], h_new[1024], c_new[1024], attn_w[512]
#define OUT_H     50257
#define OUT_C     51281
#define OUT_AW    52305

__device__ __forceinline__ float4 ld4(const float* p) {
  return *reinterpret_cast<const float4*>(p);
}
__device__ __forceinline__ float dot4(float4 a, float4 b) {
  return a.x * b.x + a.y * b.y + a.z * b.z + a.w * b.w;
}
__device__ __forceinline__ float wave_reduce(float a) {
#pragma unroll
  for (int off = 32; off > 0; off >>= 1) a += __shfl_xor(a, off, 64);
  return a;
}
__device__ __forceinline__ float sigf(float v) {
  return 1.f / (1.f + expf(-v));
}

// K1: attn_pre (blocks 0..127) ∥ ghh = W_hh·h0 + b_hh (blocks 128..255)
//     ∥ zero applied accumulator (block 256).
// ghh depends only on kernel inputs -> pulls W_hh's 16.8 MB off the
// critical path that runs through x.
__global__ __launch_bounds__(256) void pre_ghh_k(
    const float* __restrict__ attn_W, const float* __restrict__ attn_b,
    const float* __restrict__ emb, const int* __restrict__ word,
    const float* __restrict__ h0, const float* __restrict__ W_hh,
    const float* __restrict__ b_hh, float* __restrict__ ws) {
  int b = blockIdx.x;
  int t = threadIdx.x, wv = t >> 6, lane = t & 63;
  if (b < 128) {
    int row = b * 4 + wv;                       // 512 rows
    const float* Wr = attn_W + (size_t)row * 1536;
    const float* er = emb + (size_t)word[0] * 512;
    float acc = 0.f;
#pragma unroll
    for (int k = 0; k < 2; k++) {               // cols 0..511: embedded
      int c = lane * 4 + k * 256;
      acc += dot4(ld4(Wr + c), ld4(er + c));
    }
#pragma unroll
    for (int k = 2; k < 6; k++) {               // cols 512..1535: h0
      int c = lane * 4 + k * 256;
      acc += dot4(ld4(Wr + c), ld4(h0 + c - 512));
    }
    acc = wave_reduce(acc);
    if (lane == 0) ws[WS_PRE + row] = acc + attn_b[row];
  } else if (b < 256) {
    int gid = (b - 128) * 4 + wv;               // 512 waves x 8 rows = 4096
#pragma unroll
    for (int rr = 0; rr < 8; rr++) {
      int r = gid * 8 + rr;
      const float* Wh = W_hh + (size_t)r * 1024;
      float acc = 0.f;
#pragma unroll
      for (int k = 0; k < 4; k++) {
        int c = lane * 4 + k * 256;
        acc += dot4(ld4(Wh + c), ld4(h0 + c));
      }
      acc = wave_reduce(acc);
      if (lane == 0) ws[WS_GHH + r] = acc + b_hh[r];
    }
  } else {
    for (int i = t; i < 1024; i += 256) ws[WS_APPL + i] = 0.f;
  }
}

// K2: softmax (recomputed redundantly per block from pre: 2 KB, trivial)
//     + attn_apply. 64 blocks = 16 l-chunks x 4 j-blocks. Block 0 also
//     writes attn_weights to out.
__global__ __launch_bounds__(256) void sm_apply_k(
    const float* __restrict__ pre, const float* __restrict__ enc,
    float* __restrict__ out_w, float* __restrict__ applied) {
  __shared__ float wsh[512];
  __shared__ float red[4];
  __shared__ float stat[2];
  int t = threadIdx.x, lane = t & 63, wv = t >> 6;
  float v0 = pre[t], v1 = pre[t + 256];
  float m = fmaxf(v0, v1);
#pragma unroll
  for (int off = 32; off > 0; off >>= 1) m = fmaxf(m, __shfl_xor(m, off, 64));
  if (lane == 0) red[wv] = m;
  __syncthreads();
  if (t == 0) stat[0] = fmaxf(fmaxf(red[0], red[1]), fmaxf(red[2], red[3]));
  __syncthreads();
  float e0 = expf(v0 - stat[0]), e1 = expf(v1 - stat[0]);
  float s = e0 + e1;
#pragma unroll
  for (int off = 32; off > 0; off >>= 1) s += __shfl_xor(s, off, 64);
  if (lane == 0) red[wv] = s;
  __syncthreads();
  if (t == 0) stat[1] = red[0] + red[1] + red[2] + red[3];
  __syncthreads();
  float w0 = e0 / stat[1], w1 = e1 / stat[1];
  wsh[t] = w0;
  wsh[t + 256] = w1;
  if (blockIdx.x == 0) {
    out_w[t] = w0;
    out_w[t + 256] = w1;
  }
  __syncthreads();
  int jb = blockIdx.x & 3, lb = blockIdx.x >> 2;
  int j = jb * 256 + t, l0 = lb * 32;
  float acc = 0.f;
#pragma unroll 8
  for (int l = l0; l < l0 + 32; l++) acc += wsh[l] * enc[(size_t)l * 1024 + j];
  atomicAdd(applied + j, acc);
}

// K3: x[row] = relu(comb_W[row]·[emb, applied, av] + comb_b[row])  (1024 rows)
__global__ __launch_bounds__(256) void comb_mv_k(
    const float* __restrict__ comb_W, const float* __restrict__ comb_b,
    const float* __restrict__ emb, const int* __restrict__ word,
    const float* __restrict__ applied, const float* __restrict__ av,
    float* __restrict__ x) {
  int row = blockIdx.x * 4 + (threadIdx.x >> 6);
  int lane = threadIdx.x & 63;
  const float* Wr = comb_W + (size_t)row * 2048;
  const float* er = emb + (size_t)word[0] * 512;
  float acc = 0.f;
#pragma unroll
  for (int k = 0; k < 2; k++) {                 // embedded
    int c = lane * 4 + k * 256;
    acc += dot4(ld4(Wr + c), ld4(er + c));
  }
#pragma unroll
  for (int k = 2; k < 6; k++) {                 // applied
    int c = lane * 4 + k * 256;
    acc += dot4(ld4(Wr + c), ld4(applied + c - 512));
  }
#pragma unroll
  for (int k = 6; k < 8; k++) {                 // av_emb
    int c = lane * 4 + k * 256;
    acc += dot4(ld4(Wr + c), ld4(av + c - 1536));
  }
  acc = wave_reduce(acc);
  if (lane == 0) x[row] = fmaxf(acc + comb_b[row], 0.f);
}

// K4: gates = W_ih·x + b_ih + ghh (W_hh half precomputed in K1);
//     pointwise LSTM. Block t: wave wv computes gate row wv*1024+t.
__global__ __launch_bounds__(256) void gates_lstm_k(
    const float* __restrict__ Wih, const float* __restrict__ bih,
    const float* __restrict__ ghh, const float* __restrict__ x,
    const float* __restrict__ c0, float* __restrict__ out_h,
    float* __restrict__ out_c) {
  __shared__ float gsh[4];
  int t = blockIdx.x;
  int wv = threadIdx.x >> 6, lane = threadIdx.x & 63;
  size_t r = (size_t)wv * 1024 + t;             // wv: 0=i 1=f 2=g 3=o
  const float* Wi = Wih + r * 1024;
  float acc = 0.f;
#pragma unroll
  for (int k = 0; k < 4; k++) {
    int c = lane * 4 + k * 256;
    acc += dot4(ld4(Wi + c), ld4(x + c));
  }
  acc = wave_reduce(acc);
  if (lane == 0) gsh[wv] = acc + bih[r] + ghh[r];
  __syncthreads();
  if (threadIdx.x == 0) {
    float gi = sigf(gsh[0]);
    float gf = sigf(gsh[1]);
    float gg = tanhf(gsh[2]);
    float go = sigf(gsh[3]);
    float cn = gf * c0[t] + gi * gg;
    float hn = go * tanhf(cn);
    out_h[t] = hn;
    out_c[t] = cn;
  }
}

// K5: logits[row] = out_W[row]·h_new + out_b[row]; 2 rows/wave, 8 rows/block
__global__ __launch_bounds__(256) void logits_mv_k(
    const float* __restrict__ W, const float* __restrict__ bias,
    const float* __restrict__ x, float* __restrict__ y) {
  int wv = threadIdx.x >> 6, lane = threadIdx.x & 63;
  int r0 = blockIdx.x * 8 + wv * 2;
  if (r0 >= V) return;
  bool has1 = (r0 + 1) < V;
  const float* W0 = W + (size_t)r0 * 1024;
  float a0 = 0.f, a1 = 0.f;
#pragma unroll
  for (int k = 0; k < 4; k++) {
    int c = lane * 4 + k * 256;
    float4 xv = ld4(x + c);
    a0 += dot4(ld4(W0 + c), xv);
    if (has1) a1 += dot4(ld4(W0 + 1024 + c), xv);
  }
  a0 = wave_reduce(a0);
  a1 = wave_reduce(a1);
  if (lane == 0) {
    y[r0] = a0 + bias[r0];
    if (has1) y[r0 + 1] = a1 + bias[r0 + 1];
  }
}

extern "C" void kernel_launch(void* const* d_in, const int* in_sizes, int n_in,
                              void* d_out, int out_size, void* d_ws, size_t ws_size,
                              hipStream_t stream) {
  const int*   word   = (const int*)  d_in[0];
  // d_in[1] = enc_seq_len (==1 -> reference row-mask is a no-op)
  const float* av     = (const float*)d_in[2];
  const float* h0     = (const float*)d_in[3];
  const float* c0     = (const float*)d_in[4];
  const float* enc    = (const float*)d_in[5];
  const float* emb    = (const float*)d_in[6];
  const float* attn_W = (const float*)d_in[7];
  const float* attn_b = (const float*)d_in[8];
  const float* comb_W = (const float*)d_in[9];
  const float* comb_b = (const float*)d_in[10];
  const float* W_ih   = (const float*)d_in[11];
  const float* W_hh   = (const float*)d_in[12];
  const float* b_ih   = (const float*)d_in[13];
  const float* b_hh   = (const float*)d_in[14];
  const float* out_W  = (const float*)d_in[15];
  const float* out_b  = (const float*)d_in[16];

  float* ws  = (float*)d_ws;
  float* out = (float*)d_out;

  pre_ghh_k<<<257, 256, 0, stream>>>(attn_W, attn_b, emb, word, h0, W_hh,
                                     b_hh, ws);
  sm_apply_k<<<64, 256, 0, stream>>>(ws + WS_PRE, enc, out + OUT_AW,
                                     ws + WS_APPL);
  comb_mv_k<<<256, 256, 0, stream>>>(comb_W, comb_b, emb, word, ws + WS_APPL,
                                     av, ws + WS_X);
  gates_lstm_k<<<1024, 256, 0, stream>>>(W_ih, b_ih, ws + WS_GHH, ws + WS_X,
                                         c0, out + OUT_H, out + OUT_C);
  logits_mv_k<<<(V + 7) / 8, 256, 0, stream>>>(out_W, out_b, out + OUT_H, out);
}

// Round 4
// 391.803 us; speedup vs baseline: 3.6836x; 1.0080x over previous
//
#include <hip/hip_runtime.h>

// All float tensors f32 (established rounds 0-4). H=1024,E=512,A=512,L=512.
// enc_seq_len==1 -> reference row-mask is a no-op.
// R2 lesson: software grid barriers cost ~200us each on MI355X (1024 atomics
// serializing cross-XCD). Stay multi-kernel; sync at dispatch boundaries.
// R3 lesson: small kernels must be latency-tuned: 1 row/wave, float4 loads,
// >=4 blocks/CU. Serial per-wave row loops at 1 block/CU cost ~1us/row.
#define V 50257

// ---------------- workspace layout (f32 words) ----------------
#define WS_PRE    0      // attn_pre (512)
#define WS_APPL   1024   // attn_applied (1024)
#define WS_X      2048   // combine+relu output (1024)
#define WS_GHH    3072   // W_hh·h0 + b_hh (4096)

// output layout (f32): logits[50257], h_new[1024], c_new[1024], attn_w[512]
#define OUT_H     50257
#define OUT_C     51281
#define OUT_AW    52305

__device__ __forceinline__ float4 ld4(const float* p) {
  return *reinterpret_cast<const float4*>(p);
}
__device__ __forceinline__ float dot4(float4 a, float4 b) {
  return a.x * b.x + a.y * b.y + a.z * b.z + a.w * b.w;
}
__device__ __forceinline__ float wave_reduce(float a) {
#pragma unroll
  for (int off = 32; off > 0; off >>= 1) a += __shfl_xor(a, off, 64);
  return a;
}
__device__ __forceinline__ float sigf(float v) {
  return 1.f / (1.f + expf(-v));
}

// K1: attn_pre (blocks 0..127, 1 row/wave) ∥ ghh = W_hh·h0 + b_hh
//     (blocks 128..1151, 1 row/wave -> no serial row loop, 4.5 blk/CU)
//     ∥ zero applied accumulator (block 1152).
__global__ __launch_bounds__(256) void pre_ghh_k(
    const float* __restrict__ attn_W, const float* __restrict__ attn_b,
    const float* __restrict__ emb, const int* __restrict__ word,
    const float* __restrict__ h0, const float* __restrict__ W_hh,
    const float* __restrict__ b_hh, float* __restrict__ ws) {
  int b = blockIdx.x;
  int t = threadIdx.x, wv = t >> 6, lane = t & 63;
  if (b < 128) {
    int row = b * 4 + wv;                       // 512 rows
    const float* Wr = attn_W + (size_t)row * 1536;
    const float* er = emb + (size_t)word[0] * 512;
    float acc = 0.f;
#pragma unroll
    for (int k = 0; k < 2; k++) {               // cols 0..511: embedded
      int c = lane * 4 + k * 256;
      acc += dot4(ld4(Wr + c), ld4(er + c));
    }
#pragma unroll
    for (int k = 2; k < 6; k++) {               // cols 512..1535: h0
      int c = lane * 4 + k * 256;
      acc += dot4(ld4(Wr + c), ld4(h0 + c - 512));
    }
    acc = wave_reduce(acc);
    if (lane == 0) ws[WS_PRE + row] = acc + attn_b[row];
  } else if (b < 1152) {
    int r = (b - 128) * 4 + wv;                 // 4096 gate rows, 1 per wave
    const float* Wh = W_hh + (size_t)r * 1024;
    float acc = 0.f;
#pragma unroll
    for (int k = 0; k < 4; k++) {
      int c = lane * 4 + k * 256;
      acc += dot4(ld4(Wh + c), ld4(h0 + c));
    }
    acc = wave_reduce(acc);
    if (lane == 0) ws[WS_GHH + r] = acc + b_hh[r];
  } else {
    for (int i = t; i < 1024; i += 256) ws[WS_APPL + i] = 0.f;
  }
}

// K2: redundant per-block softmax (2 KB read, trivial) + attn_apply.
// 64 blocks, each handles 8 l-rows x ALL 1024 j (float4 per thread).
// Block 0 also writes attn_weights to out.
__global__ __launch_bounds__(256) void sm_apply_k(
    const float* __restrict__ pre, const float* __restrict__ enc,
    float* __restrict__ out_w, float* __restrict__ applied) {
  __shared__ float wsh[512];
  __shared__ float red[4];
  __shared__ float stat[2];
  int t = threadIdx.x, lane = t & 63, wv = t >> 6;
  float v0 = pre[t], v1 = pre[t + 256];
  float m = fmaxf(v0, v1);
#pragma unroll
  for (int off = 32; off > 0; off >>= 1) m = fmaxf(m, __shfl_xor(m, off, 64));
  if (lane == 0) red[wv] = m;
  __syncthreads();
  if (t == 0) stat[0] = fmaxf(fmaxf(red[0], red[1]), fmaxf(red[2], red[3]));
  __syncthreads();
  float e0 = expf(v0 - stat[0]), e1 = expf(v1 - stat[0]);
  float s = e0 + e1;
#pragma unroll
  for (int off = 32; off > 0; off >>= 1) s += __shfl_xor(s, off, 64);
  if (lane == 0) red[wv] = s;
  __syncthreads();
  if (t == 0) stat[1] = red[0] + red[1] + red[2] + red[3];
  __syncthreads();
  float w0 = e0 / stat[1], w1 = e1 / stat[1];
  wsh[t] = w0;
  wsh[t + 256] = w1;
  if (blockIdx.x == 0) {
    out_w[t] = w0;
    out_w[t + 256] = w1;
  }
  __syncthreads();
  int l0 = blockIdx.x * 8;                      // 64 blocks x 8 rows = 512
  float ax = 0.f, ay = 0.f, az = 0.f, aw = 0.f;
#pragma unroll
  for (int i = 0; i < 8; i++) {                 // 8x16B in flight per thread
    float wl = wsh[l0 + i];                     // LDS broadcast (uniform)
    float4 e = ld4(enc + (size_t)(l0 + i) * 1024 + t * 4);
    ax += wl * e.x; ay += wl * e.y; az += wl * e.z; aw += wl * e.w;
  }
  atomicAdd(applied + t * 4 + 0, ax);
  atomicAdd(applied + t * 4 + 1, ay);
  atomicAdd(applied + t * 4 + 2, az);
  atomicAdd(applied + t * 4 + 3, aw);
}

// K3: x[row] = relu(comb_W[row]·[emb, applied, av] + comb_b[row])  (1024 rows)
__global__ __launch_bounds__(256) void comb_mv_k(
    const float* __restrict__ comb_W, const float* __restrict__ comb_b,
    const float* __restrict__ emb, const int* __restrict__ word,
    const float* __restrict__ applied, const float* __restrict__ av,
    float* __restrict__ x) {
  int row = blockIdx.x * 4 + (threadIdx.x >> 6);
  int lane = threadIdx.x & 63;
  const float* Wr = comb_W + (size_t)row * 2048;
  const float* er = emb + (size_t)word[0] * 512;
  float acc = 0.f;
#pragma unroll
  for (int k = 0; k < 2; k++) {                 // embedded
    int c = lane * 4 + k * 256;
    acc += dot4(ld4(Wr + c), ld4(er + c));
  }
#pragma unroll
  for (int k = 2; k < 6; k++) {                 // applied
    int c = lane * 4 + k * 256;
    acc += dot4(ld4(Wr + c), ld4(applied + c - 512));
  }
#pragma unroll
  for (int k = 6; k < 8; k++) {                 // av_emb
    int c = lane * 4 + k * 256;
    acc += dot4(ld4(Wr + c), ld4(av + c - 1536));
  }
  acc = wave_reduce(acc);
  if (lane == 0) x[row] = fmaxf(acc + comb_b[row], 0.f);
}

// K4: gates = W_ih·x + b_ih + ghh (W_hh half precomputed in K1);
//     pointwise LSTM. Block t: wave wv computes gate row wv*1024+t.
__global__ __launch_bounds__(256) void gates_lstm_k(
    const float* __restrict__ Wih, const float* __restrict__ bih,
    const float* __restrict__ ghh, const float* __restrict__ x,
    const float* __restrict__ c0, float* __restrict__ out_h,
    float* __restrict__ out_c) {
  __shared__ float gsh[4];
  int t = blockIdx.x;
  int wv = threadIdx.x >> 6, lane = threadIdx.x & 63;
  size_t r = (size_t)wv * 1024 + t;             // wv: 0=i 1=f 2=g 3=o
  const float* Wi = Wih + r * 1024;
  float acc = 0.f;
#pragma unroll
  for (int k = 0; k < 4; k++) {
    int c = lane * 4 + k * 256;
    acc += dot4(ld4(Wi + c), ld4(x + c));
  }
  acc = wave_reduce(acc);
  if (lane == 0) gsh[wv] = acc + bih[r] + ghh[r];
  __syncthreads();
  if (threadIdx.x == 0) {
    float gi = sigf(gsh[0]);
    float gf = sigf(gsh[1]);
    float gg = tanhf(gsh[2]);
    float go = sigf(gsh[3]);
    float cn = gf * c0[t] + gi * gg;
    float hn = go * tanhf(cn);
    out_h[t] = hn;
    out_c[t] = cn;
  }
}

// K5: logits[row] = out_W[row]·h_new + out_b[row]; 4 rows/wave (256 B/lane
// in flight), 16 rows/block.
__global__ __launch_bounds__(256) void logits_mv_k(
    const float* __restrict__ W, const float* __restrict__ bias,
    const float* __restrict__ x, float* __restrict__ y) {
  int wv = threadIdx.x >> 6, lane = threadIdx.x & 63;
  int r0 = blockIdx.x * 16 + wv * 4;
  if (r0 >= V) return;
  int nr = V - r0;                              // rows available (>=1)
  const float* W0 = W + (size_t)r0 * 1024;
  float a0 = 0.f, a1 = 0.f, a2 = 0.f, a3 = 0.f;
  if (nr >= 4) {
#pragma unroll
    for (int k = 0; k < 4; k++) {
      int c = lane * 4 + k * 256;
      float4 xv = ld4(x + c);
      a0 += dot4(ld4(W0 + c), xv);
      a1 += dot4(ld4(W0 + 1024 + c), xv);
      a2 += dot4(ld4(W0 + 2048 + c), xv);
      a3 += dot4(ld4(W0 + 3072 + c), xv);
    }
  } else {
#pragma unroll
    for (int k = 0; k < 4; k++) {
      int c = lane * 4 + k * 256;
      float4 xv = ld4(x + c);
      a0 += dot4(ld4(W0 + c), xv);
      if (nr > 1) a1 += dot4(ld4(W0 + 1024 + c), xv);
      if (nr > 2) a2 += dot4(ld4(W0 + 2048 + c), xv);
    }
  }
  a0 = wave_reduce(a0);
  a1 = wave_reduce(a1);
  a2 = wave_reduce(a2);
  a3 = wave_reduce(a3);
  if (lane == 0) {
    y[r0] = a0 + bias[r0];
    if (nr > 1) y[r0 + 1] = a1 + bias[r0 + 1];
    if (nr > 2) y[r0 + 2] = a2 + bias[r0 + 2];
    if (nr > 3) y[r0 + 3] = a3 + bias[r0 + 3];
  }
}

extern "C" void kernel_launch(void* const* d_in, const int* in_sizes, int n_in,
                              void* d_out, int out_size, void* d_ws, size_t ws_size,
                              hipStream_t stream) {
  const int*   word   = (const int*)  d_in[0];
  // d_in[1] = enc_seq_len (==1 -> reference row-mask is a no-op)
  const float* av     = (const float*)d_in[2];
  const float* h0     = (const float*)d_in[3];
  const float* c0     = (const float*)d_in[4];
  const float* enc    = (const float*)d_in[5];
  const float* emb    = (const float*)d_in[6];
  const float* attn_W = (const float*)d_in[7];
  const float* attn_b = (const float*)d_in[8];
  const float* comb_W = (const float*)d_in[9];
  const float* comb_b = (const float*)d_in[10];
  const float* W_ih   = (const float*)d_in[11];
  const float* W_hh   = (const float*)d_in[12];
  const float* b_ih   = (const float*)d_in[13];
  const float* b_hh   = (const float*)d_in[14];
  const float* out_W  = (const float*)d_in[15];
  const float* out_b  = (const float*)d_in[16];

  float* ws  = (float*)d_ws;
  float* out = (float*)d_out;

  pre_ghh_k<<<1153, 256, 0, stream>>>(attn_W, attn_b, emb, word, h0, W_hh,
                                      b_hh, ws);
  sm_apply_k<<<64, 256, 0, stream>>>(ws + WS_PRE, enc, out + OUT_AW,
                                     ws + WS_APPL);
  comb_mv_k<<<256, 256, 0, stream>>>(comb_W, comb_b, emb, word, ws + WS_APPL,
                                     av, ws + WS_X);
  gates_lstm_k<<<1024, 256, 0, stream>>>(W_ih, b_ih, ws + WS_GHH, ws + WS_X,
                                         c0, out + OUT_H, out + OUT_C);
  logits_mv_k<<<(V + 15) / 16, 256, 0, stream>>>(out_W, out_b, out + OUT_H,
                                                 out);
}

// Round 6
// 380.941 us; speedup vs baseline: 3.7887x; 1.0285x over previous
//
#include <hip/hip_runtime.h>

// All float tensors f32. H=1024,E=512,A=512,L=512. enc_seq_len==1 -> mask no-op.
// R2 lesson: software grid barriers cost ~200us each (cross-XCD atomics) -> stay
// multi-kernel, sync at dispatch boundaries (gap ~2-3us each, measured R0->R3).
// R4 lesson: latency-tuning small kernels is null; suspect K5 streaming BW.
// R5 lesson: __builtin_nontemporal_load needs a native ext_vector_type, not
// HIP's float4 class.
#define V 50257

// ---------------- workspace layout (f32 words) ----------------
#define WS_PRE    0      // attn_pre (512)
#define WS_X      2048   // combine+relu output (1024)
#define WS_GHH    3072   // W_hh·h0 + b_hh (4096)
#define WS_PART   8192   // 16 x 1024 partial attn_applied (owned slots, no atomics)

// output layout (f32): logits[50257], h_new[1024], c_new[1024], attn_w[512]
#define OUT_H     50257
#define OUT_C     51281
#define OUT_AW    52305

typedef float vf4 __attribute__((ext_vector_type(4)));

__device__ __forceinline__ float4 ld4(const float* p) {
  return *reinterpret_cast<const float4*>(p);
}
// Nontemporal 16B load via native ext-vector (builtin rejects HIP float4).
__device__ __forceinline__ float4 ld4_nt(const float* p) {
  vf4 v = __builtin_nontemporal_load(reinterpret_cast<const vf4*>(p));
  return make_float4(v.x, v.y, v.z, v.w);
}
__device__ __forceinline__ float dot4(float4 a, float4 b) {
  return a.x * b.x + a.y * b.y + a.z * b.z + a.w * b.w;
}
__device__ __forceinline__ float wave_reduce(float a) {
#pragma unroll
  for (int off = 32; off > 0; off >>= 1) a += __shfl_xor(a, off, 64);
  return a;
}
__device__ __forceinline__ float sigf(float v) {
  return 1.f / (1.f + expf(-v));
}

// K1: attn_pre (blocks 0..127, 1 row/wave) ∥ ghh = W_hh·h0 + b_hh
//     (blocks 128..1151, 1 row/wave).
__global__ __launch_bounds__(256) void pre_ghh_k(
    const float* __restrict__ attn_W, const float* __restrict__ attn_b,
    const float* __restrict__ emb, const int* __restrict__ word,
    const float* __restrict__ h0, const float* __restrict__ W_hh,
    const float* __restrict__ b_hh, float* __restrict__ ws) {
  int b = blockIdx.x;
  int t = threadIdx.x, wv = t >> 6, lane = t & 63;
  if (b < 128) {
    int row = b * 4 + wv;                       // 512 rows
    const float* Wr = attn_W + (size_t)row * 1536;
    const float* er = emb + (size_t)word[0] * 512;
    float acc = 0.f;
#pragma unroll
    for (int k = 0; k < 2; k++) {               // cols 0..511: embedded
      int c = lane * 4 + k * 256;
      acc += dot4(ld4(Wr + c), ld4(er + c));
    }
#pragma unroll
    for (int k = 2; k < 6; k++) {               // cols 512..1535: h0
      int c = lane * 4 + k * 256;
      acc += dot4(ld4(Wr + c), ld4(h0 + c - 512));
    }
    acc = wave_reduce(acc);
    if (lane == 0) ws[WS_PRE + row] = acc + attn_b[row];
  } else {
    int r = (b - 128) * 4 + wv;                 // 4096 gate rows, 1 per wave
    const float* Wh = W_hh + (size_t)r * 1024;
    float acc = 0.f;
#pragma unroll
    for (int k = 0; k < 4; k++) {
      int c = lane * 4 + k * 256;
      acc += dot4(ld4(Wh + c), ld4(h0 + c));
    }
    acc = wave_reduce(acc);
    if (lane == 0) ws[WS_GHH + r] = acc + b_hh[r];
  }
}

// K2: redundant per-block softmax (2 KB, trivial) + attn_apply partials.
// 64 blocks = 16 l-chunks x 4 j-quarters; block (lb,jb) OWNS part[lb][jb*256..]
// -> non-atomic overwrite, no zeroing needed. Block 0 writes attn_weights out.
__global__ __launch_bounds__(256) void sm_apply_k(
    const float* __restrict__ pre, const float* __restrict__ enc,
    float* __restrict__ out_w, float* __restrict__ part) {
  __shared__ float wsh[512];
  __shared__ float red[4];
  __shared__ float stat[2];
  int t = threadIdx.x, lane = t & 63, wv = t >> 6;
  float v0 = pre[t], v1 = pre[t + 256];
  float m = fmaxf(v0, v1);
#pragma unroll
  for (int off = 32; off > 0; off >>= 1) m = fmaxf(m, __shfl_xor(m, off, 64));
  if (lane == 0) red[wv] = m;
  __syncthreads();
  if (t == 0) stat[0] = fmaxf(fmaxf(red[0], red[1]), fmaxf(red[2], red[3]));
  __syncthreads();
  float e0 = expf(v0 - stat[0]), e1 = expf(v1 - stat[0]);
  float s = e0 + e1;
#pragma unroll
  for (int off = 32; off > 0; off >>= 1) s += __shfl_xor(s, off, 64);
  if (lane == 0) red[wv] = s;
  __syncthreads();
  if (t == 0) stat[1] = red[0] + red[1] + red[2] + red[3];
  __syncthreads();
  float w0 = e0 / stat[1], w1 = e1 / stat[1];
  wsh[t] = w0;
  wsh[t + 256] = w1;
  if (blockIdx.x == 0) {
    out_w[t] = w0;
    out_w[t + 256] = w1;
  }
  __syncthreads();
  int lb = blockIdx.x >> 2, jb = blockIdx.x & 3;
  int l0 = lb * 32;
  int j = jb * 256 + t;
  float acc = 0.f;
#pragma unroll 8
  for (int l = 0; l < 32; l++)
    acc += wsh[l0 + l] * enc[(size_t)(l0 + l) * 1024 + j];
  part[lb * 1024 + j] = acc;                    // owned slot, no atomic
}

// K3: x[row] = relu(comb_W[row]·[emb, applied, av] + comb_b[row]); applied is
// reconstructed inline as the sum of 16 L2-hot partials (64 KB total).
__global__ __launch_bounds__(256) void comb_mv_k(
    const float* __restrict__ comb_W, const float* __restrict__ comb_b,
    const float* __restrict__ emb, const int* __restrict__ word,
    const float* __restrict__ part, const float* __restrict__ av,
    float* __restrict__ x) {
  int row = blockIdx.x * 4 + (threadIdx.x >> 6);
  int lane = threadIdx.x & 63;
  const float* Wr = comb_W + (size_t)row * 2048;
  const float* er = emb + (size_t)word[0] * 512;
  float acc = 0.f;
#pragma unroll
  for (int k = 0; k < 2; k++) {                 // embedded
    int c = lane * 4 + k * 256;
    acc += dot4(ld4(Wr + c), ld4(er + c));
  }
#pragma unroll
  for (int k = 2; k < 6; k++) {                 // applied = sum of 16 partials
    int c = lane * 4 + k * 256;
    int j = c - 512;
    float4 s = ld4(part + j);
#pragma unroll
    for (int p = 1; p < 16; p++) {
      float4 v = ld4(part + p * 1024 + j);
      s.x += v.x; s.y += v.y; s.z += v.z; s.w += v.w;
    }
    acc += dot4(ld4(Wr + c), s);
  }
#pragma unroll
  for (int k = 6; k < 8; k++) {                 // av_emb
    int c = lane * 4 + k * 256;
    acc += dot4(ld4(Wr + c), ld4(av + c - 1536));
  }
  acc = wave_reduce(acc);
  if (lane == 0) x[row] = fmaxf(acc + comb_b[row], 0.f);
}

// K4: gates = W_ih·x + b_ih + ghh; pointwise LSTM. Block t, wave wv = gate row.
__global__ __launch_bounds__(256) void gates_lstm_k(
    const float* __restrict__ Wih, const float* __restrict__ bih,
    const float* __restrict__ ghh, const float* __restrict__ x,
    const float* __restrict__ c0, float* __restrict__ out_h,
    float* __restrict__ out_c) {
  __shared__ float gsh[4];
  int t = blockIdx.x;
  int wv = threadIdx.x >> 6, lane = threadIdx.x & 63;
  size_t r = (size_t)wv * 1024 + t;             // wv: 0=i 1=f 2=g 3=o
  const float* Wi = Wih + r * 1024;
  float acc = 0.f;
#pragma unroll
  for (int k = 0; k < 4; k++) {
    int c = lane * 4 + k * 256;
    acc += dot4(ld4(Wi + c), ld4(x + c));
  }
  acc = wave_reduce(acc);
  if (lane == 0) gsh[wv] = acc + bih[r] + ghh[r];
  __syncthreads();
  if (threadIdx.x == 0) {
    float gi = sigf(gsh[0]);
    float gf = sigf(gsh[1]);
    float gg = tanhf(gsh[2]);
    float go = sigf(gsh[3]);
    float cn = gf * c0[t] + gi * gg;
    float hn = go * tanhf(cn);
    out_h[t] = hn;
    out_c[t] = cn;
  }
}

// K5: logits. 8 rows/wave (512 B/lane in flight), x hoisted to registers,
// nontemporal W loads (zero-reuse 206 MB stream -> don't thrash L2).
__global__ __launch_bounds__(256) void logits_mv_k(
    const float* __restrict__ W, const float* __restrict__ bias,
    const float* __restrict__ x, float* __restrict__ y) {
  int wv = threadIdx.x >> 6, lane = threadIdx.x & 63;
  int r0 = blockIdx.x * 32 + wv * 8;
  if (r0 >= V) return;
  int nr = V - r0;                              // rows available (uniform/wave)
  const float* W0 = W + (size_t)r0 * 1024;
  float4 xv0 = ld4(x + lane * 4);
  float4 xv1 = ld4(x + lane * 4 + 256);
  float4 xv2 = ld4(x + lane * 4 + 512);
  float4 xv3 = ld4(x + lane * 4 + 768);
  float a0 = 0.f, a1 = 0.f, a2 = 0.f, a3 = 0.f;
  float a4 = 0.f, a5 = 0.f, a6 = 0.f, a7 = 0.f;
  if (nr >= 8) {
#pragma unroll
    for (int k = 0; k < 4; k++) {
      int c = lane * 4 + k * 256;
      float4 xv = (k == 0) ? xv0 : (k == 1) ? xv1 : (k == 2) ? xv2 : xv3;
      a0 += dot4(ld4_nt(W0 + 0 * 1024 + c), xv);
      a1 += dot4(ld4_nt(W0 + 1 * 1024 + c), xv);
      a2 += dot4(ld4_nt(W0 + 2 * 1024 + c), xv);
      a3 += dot4(ld4_nt(W0 + 3 * 1024 + c), xv);
      a4 += dot4(ld4_nt(W0 + 4 * 1024 + c), xv);
      a5 += dot4(ld4_nt(W0 + 5 * 1024 + c), xv);
      a6 += dot4(ld4_nt(W0 + 6 * 1024 + c), xv);
      a7 += dot4(ld4_nt(W0 + 7 * 1024 + c), xv);
    }
  } else {
#pragma unroll
    for (int k = 0; k < 4; k++) {
      int c = lane * 4 + k * 256;
      float4 xv = (k == 0) ? xv0 : (k == 1) ? xv1 : (k == 2) ? xv2 : xv3;
      a0 += dot4(ld4_nt(W0 + 0 * 1024 + c), xv);
      if (nr > 1) a1 += dot4(ld4_nt(W0 + 1 * 1024 + c), xv);
      if (nr > 2) a2 += dot4(ld4_nt(W0 + 2 * 1024 + c), xv);
      if (nr > 3) a3 += dot4(ld4_nt(W0 + 3 * 1024 + c), xv);
      if (nr > 4) a4 += dot4(ld4_nt(W0 + 4 * 1024 + c), xv);
      if (nr > 5) a5 += dot4(ld4_nt(W0 + 5 * 1024 + c), xv);
      if (nr > 6) a6 += dot4(ld4_nt(W0 + 6 * 1024 + c), xv);
    }
  }
  a0 = wave_reduce(a0);
  a1 = wave_reduce(a1);
  a2 = wave_reduce(a2);
  a3 = wave_reduce(a3);
  a4 = wave_reduce(a4);
  a5 = wave_reduce(a5);
  a6 = wave_reduce(a6);
  a7 = wave_reduce(a7);
  if (lane == 0) {
    y[r0] = a0 + bias[r0];
    if (nr > 1) y[r0 + 1] = a1 + bias[r0 + 1];
    if (nr > 2) y[r0 + 2] = a2 + bias[r0 + 2];
    if (nr > 3) y[r0 + 3] = a3 + bias[r0 + 3];
    if (nr > 4) y[r0 + 4] = a4 + bias[r0 + 4];
    if (nr > 5) y[r0 + 5] = a5 + bias[r0 + 5];
    if (nr > 6) y[r0 + 6] = a6 + bias[r0 + 6];
    if (nr > 7) y[r0 + 7] = a7 + bias[r0 + 7];
  }
}

extern "C" void kernel_launch(void* const* d_in, const int* in_sizes, int n_in,
                              void* d_out, int out_size, void* d_ws, size_t ws_size,
                              hipStream_t stream) {
  const int*   word   = (const int*)  d_in[0];
  // d_in[1] = enc_seq_len (==1 -> reference row-mask is a no-op)
  const float* av     = (const float*)d_in[2];
  const float* h0     = (const float*)d_in[3];
  const float* c0     = (const float*)d_in[4];
  const float* enc    = (const float*)d_in[5];
  const float* emb    = (const float*)d_in[6];
  const float* attn_W = (const float*)d_in[7];
  const float* attn_b = (const float*)d_in[8];
  const float* comb_W = (const float*)d_in[9];
  const float* comb_b = (const float*)d_in[10];
  const float* W_ih   = (const float*)d_in[11];
  const float* W_hh   = (const float*)d_in[12];
  const float* b_ih   = (const float*)d_in[13];
  const float* b_hh   = (const float*)d_in[14];
  const float* out_W  = (const float*)d_in[15];
  const float* out_b  = (const float*)d_in[16];

  float* ws  = (float*)d_ws;
  float* out = (float*)d_out;

  pre_ghh_k<<<1152, 256, 0, stream>>>(attn_W, attn_b, emb, word, h0, W_hh,
                                      b_hh, ws);
  sm_apply_k<<<64, 256, 0, stream>>>(ws + WS_PRE, enc, out + OUT_AW,
                                     ws + WS_PART);
  comb_mv_k<<<256, 256, 0, stream>>>(comb_W, comb_b, emb, word, ws + WS_PART,
                                     av, ws + WS_X);
  gates_lstm_k<<<1024, 256, 0, stream>>>(W_ih, b_ih, ws + WS_GHH, ws + WS_X,
                                         c0, out + OUT_H, out + OUT_C);
  logits_mv_k<<<(V + 31) / 32, 256, 0, stream>>>(out_W, out_b, out + OUT_H,
                                                 out);
}